// Round 7
// baseline (82.473 us; speedup 1.0000x reference)
//
#include <hip/hip_runtime.h>
#include <hip/hip_fp16.h>

// Problem constants (fixed by the reference)
constexpr int Bsz  = 512;
constexpr int Nn   = 256;   // agents
constexpr int FINc = 32;
constexpr int H1c  = 16;
constexpr int Gc   = 8;
constexpr int FOUTc= 16;
constexpr int Kc   = 3;
constexpr int ACTc = 5;

// One block per batch. 1024 threads = 16 waves; 2 blocks/CU -> 32 waves/CU (max).
// __launch_bounds__(1024, 8) forces VGPR <= 64 so 8 waves/SIMD actually fit.
// S-pass: wave (rg, cg) owns rows [32rg..32rg+32) x cols [128cg..+128),
// lane owns 2 cols (float2, 8 B/lane coalesced). Partials stored f16 (32 KB).
__global__ __launch_bounds__(1024, 8)
void cpn_kernel(const float* __restrict__ x,  const float* __restrict__ S,
                const float* __restrict__ W1, const float* __restrict__ b1,
                const float* __restrict__ W2, const float* __restrict__ b2,
                const float* __restrict__ Hgf,const float* __restrict__ bgf,
                const float* __restrict__ Wa, const float* __restrict__ ba,
                float* __restrict__ out)
{
    const int b    = blockIdx.x;
    const int tid  = threadIdx.x;
    const int wid  = tid >> 6;       // 0..15
    const int lane = tid & 63;
    const int rg   = wid >> 1;       // 0..7  rows [32rg, 32rg+32)
    const int cg   = wid & 1;        // 0..1  cols [128cg, 128cg+128)
    const int n    = tid;            // agent for phases A/C (tid < 256 only)

    __shared__ __align__(16) float  zA[Nn][Gc];        // z0 f32 (8 KB)
    __shared__ __align__(16) float  zB[Nn][Gc];        // z1 f32 (8 KB)
    __shared__ __align__(16) __half zpart[8][Gc][Nn];  // f16 partials (32 KB) -> 48 KB total

    // ---------------- Phase A: compress MLP, register-lean streaming (tid<256) ----------
    if (tid < Nn) {
        const float4* xp = reinterpret_cast<const float4*>(x + ((size_t)b * Nn + n) * FINc);
        float h1v[H1c];
        #pragma unroll
        for (int h = 0; h < H1c; ++h) h1v[h] = b1[h];
        #pragma unroll
        for (int i = 0; i < FINc / 4; ++i) {           // stream x, 4 floats at a time
            const float4 v = xp[i];
            #pragma unroll
            for (int h = 0; h < H1c; ++h) {
                h1v[h] = fmaf(W1[h*FINc + 4*i+0], v.x, h1v[h]);
                h1v[h] = fmaf(W1[h*FINc + 4*i+1], v.y, h1v[h]);
                h1v[h] = fmaf(W1[h*FINc + 4*i+2], v.z, h1v[h]);
                h1v[h] = fmaf(W1[h*FINc + 4*i+3], v.w, h1v[h]);
            }
        }
        #pragma unroll
        for (int h = 0; h < H1c; ++h) h1v[h] = fmaxf(h1v[h], 0.0f);
        #pragma unroll
        for (int g = 0; g < Gc; ++g) {
            float a = b2[g];
            #pragma unroll
            for (int h = 0; h < H1c; ++h) a = fmaf(W2[g*H1c + h], h1v[h], a);
            zA[n][g] = fmaxf(a, 0.0f);
        }
    }
    __syncthreads();

    // ---------------- S passes: z_k = z_{k-1} @ S (all 16 waves) ----------------
    auto spass = [&](const float (*zsrc)[Gc]) {
        float acc[Gc][2];
        #pragma unroll
        for (int g = 0; g < Gc; ++g) { acc[g][0] = 0.0f; acc[g][1] = 0.0f; }

        const float* srow = S + ((size_t)b * Nn + rg * 32) * Nn + cg * 128 + 2 * lane;
        #pragma unroll
        for (int i = 0; i < 32; ++i) {
            const float2 sv = *reinterpret_cast<const float2*>(srow);  // coalesced 8B/lane
            srow += Nn;
            const int nn = rg * 32 + i;
            const float4 za = *reinterpret_cast<const float4*>(&zsrc[nn][0]); // b128 broadcast
            const float4 zb = *reinterpret_cast<const float4*>(&zsrc[nn][4]);
            const float zg[Gc] = {za.x, za.y, za.z, za.w, zb.x, zb.y, zb.z, zb.w};
            #pragma unroll
            for (int g = 0; g < Gc; ++g) {
                acc[g][0] = fmaf(zg[g], sv.x, acc[g][0]);
                acc[g][1] = fmaf(zg[g], sv.y, acc[g][1]);
            }
        }
        // disjoint f16 partial stores: __half2 (4 B) per g, consecutive lanes -> consecutive banks
        #pragma unroll
        for (int g = 0; g < Gc; ++g) {
            *reinterpret_cast<__half2*>(&zpart[rg][g][cg * 128 + 2 * lane]) =
                __float22half2_rn(make_float2(acc[g][0], acc[g][1]));
        }
    };

    auto merge = [&](float* zr) {      // sum 8 row-group partials (tid<256)
        #pragma unroll
        for (int g = 0; g < Gc; ++g) {
            float a = 0.0f;
            #pragma unroll
            for (int r = 0; r < 8; ++r) a += __half2float(zpart[r][g][n]);
            zr[g] = a;
        }
    };

    spass(zA);
    __syncthreads();
    if (tid < Nn) {
        float z1r[Gc];
        merge(z1r);
        #pragma unroll
        for (int g = 0; g < Gc; ++g) zB[n][g] = z1r[g];    // publish z1
    }
    __syncthreads();                                        // guards zB + zpart reuse
    spass(zB);
    __syncthreads();

    // ---------------- Phase C: graph filter + action head (tid<256) ----------------
    if (tid < Nn) {
        float z2r[Gc];
        merge(z2r);

        const float4 a0 = *reinterpret_cast<const float4*>(&zA[n][0]);
        const float4 a1 = *reinterpret_cast<const float4*>(&zA[n][4]);
        const float4 c0 = *reinterpret_cast<const float4*>(&zB[n][0]);
        const float4 c1 = *reinterpret_cast<const float4*>(&zB[n][4]);
        const float z0g[Gc] = {a0.x, a0.y, a0.z, a0.w, a1.x, a1.y, a1.z, a1.w};
        const float z1g[Gc] = {c0.x, c0.y, c0.z, c0.w, c1.x, c1.y, c1.z, c1.w};

        float y[FOUTc];
        #pragma unroll
        for (int f = 0; f < FOUTc; ++f) y[f] = bgf[f];
        #pragma unroll
        for (int g = 0; g < Gc; ++g) {
            #pragma unroll
            for (int f = 0; f < FOUTc; ++f) y[f] = fmaf(Hgf[f*(Kc*Gc) + 0*Gc + g], z0g[g], y[f]);
        }
        #pragma unroll
        for (int g = 0; g < Gc; ++g) {
            #pragma unroll
            for (int f = 0; f < FOUTc; ++f) y[f] = fmaf(Hgf[f*(Kc*Gc) + 1*Gc + g], z1g[g], y[f]);
        }
        #pragma unroll
        for (int g = 0; g < Gc; ++g) {
            #pragma unroll
            for (int f = 0; f < FOUTc; ++f) y[f] = fmaf(Hgf[f*(Kc*Gc) + 2*Gc + g], z2r[g], y[f]);
        }
        #pragma unroll
        for (int f = 0; f < FOUTc; ++f) y[f] = fmaxf(y[f], 0.0f);

        float* op = out + ((size_t)b * Nn + n) * ACTc;
        #pragma unroll
        for (int a = 0; a < ACTc; ++a) {
            float acc = ba[a];
            #pragma unroll
            for (int f = 0; f < FOUTc; ++f) acc = fmaf(Wa[a*FOUTc + f], y[f], acc);
            op[a] = acc;
        }
    }
}

extern "C" void kernel_launch(void* const* d_in, const int* in_sizes, int n_in,
                              void* d_out, int out_size, void* d_ws, size_t ws_size,
                              hipStream_t stream) {
    const float* x   = (const float*)d_in[0];
    const float* S   = (const float*)d_in[1];
    const float* W1  = (const float*)d_in[2];
    const float* b1  = (const float*)d_in[3];
    const float* W2  = (const float*)d_in[4];
    const float* b2  = (const float*)d_in[5];
    const float* Hgf = (const float*)d_in[6];
    const float* bgf = (const float*)d_in[7];
    const float* Wa  = (const float*)d_in[8];
    const float* ba  = (const float*)d_in[9];

    cpn_kernel<<<dim3(Bsz), dim3(1024), 0, stream>>>(
        x, S, W1, b1, W2, b2, Hgf, bgf, Wa, ba, (float*)d_out);
}